// Round 5
// baseline (283.969 us; speedup 1.0000x reference)
//
#include <hip/hip_runtime.h>

// CRF forward-score + gold-score, MI355X (gfx950).
//
// R5: pin E in VGPRs. R4's counters showed VGPR_Count=48 — the allocator
// SANK the E=exp(trans) computation into the K-loop (each element used once
// per iteration, trans loop-invariant & L1-hot, v_exp is 1 instr => LLVM
// remats instead of keeping 64 regs live), costing ~64 extra v_exp + loads
// per step (700 cyc/step, VALUBusy 60%). The opaque asm "+v" pin below
// makes each E value non-rematerializable, forcing it live in a VGPR
// (budget 512 via __launch_bounds__(64,1); demand ~110 -> no spill).
//
// Recurrence (exp-domain, fresh power-of-two normalization):
//   z_t[i]  = sum_j E[i][j] * beta_{t-1}[j]   (E = exp(T), 64 VGPRs/lane)
//   e_t     = exponent(z_t[0])                (readlane 0 -> SALU extract)
//   beta_t  = z_t * exp(u_t) * 2^{-e_t},  esum += e_t  (int, exact)
//   forward = log(sum_i beta_T[i]) + esum*ln2
// Fresh normalizer => memoryless => stable (R2's stale 1/z0_{t-1} was a
// |root|=1 oscillator -> NaN). exp(u) in e^±5, pow2 scale absorbs growth:
// beta <= ~7e6, z <= ~6e10 — fp32-safe. Sentinels (-10000) underflow to
// exact 0 in E, matching the fp32 reference's own underflow.
//
// beta all-gather: v_readlane -> SGPR, SGPR feeds v_fmac_f32 directly
// (1 scalar operand per VALU instr is legal). No LDS in the loop (R3 was
// LDS-pipe-bound: 4 waves/CU x 16 ds_read_b128 ~ 770 cyc/step).
// Ideal body: 64 readlane + 64 fmac + ~17 misc ~= 300 cyc/step.
//
// One wave per batch: 1024 blocks x 64 threads -> 1 wave/SIMD.
// Feat prefetch ring depth 7, outer 73 x inner unroll 7 (511 = 7*73) so
// ring indices constant-fold. exp(u_{t+1}) precomputed one step early
// (feats don't feed back -> no stability issue).

#define BB 1024
#define TT 512
#define KK 64
#define START_TAG 62

// broadcast lane l's float to all lanes via SGPR (l folds to a literal)
#define RLF(v, l) __uint_as_float((unsigned)__builtin_amdgcn_readlane((int)__float_as_uint(v), (l)))

__global__ __launch_bounds__(64, 1) void crf_forward_kernel(
    const float* __restrict__ feats,   // [B, T, K]
    const int*   __restrict__ tags,    // [B, T]
    const float* __restrict__ trans,   // [K, K]  trans[i*K+j] = score j -> i
    float*       __restrict__ diff)    // [B]  forward - gold
{
  const int lane = threadIdx.x;        // 0..63 == tag index
  const int b    = blockIdx.x;

  // ---- E row: e[j] = exp(trans[lane][j]), pinned into VGPRs ----
  float e[KK];
  {
    const float4* trow = (const float4*)(trans + lane * KK);
    #pragma unroll
    for (int jc = 0; jc < 16; ++jc) {
      float4 tv = trow[jc];
      e[4 * jc + 0] = __expf(tv.x);
      e[4 * jc + 1] = __expf(tv.y);
      e[4 * jc + 2] = __expf(tv.z);
      e[4 * jc + 3] = __expf(tv.w);
    }
  }
  // Opaque pin: forces each value into a live VGPR; kills rematerialization.
  #pragma unroll
  for (int j = 0; j < KK; ++j) asm volatile("" : "+v"(e[j]));

  const float* fb = feats + (size_t)b * TT * KK + lane;

  // ---- prefetch ring: slot (t-1)%7 holds u_t ----
  float upf[7];
  #pragma unroll
  for (int d = 0; d < 7; ++d) upf[d] = fb[(size_t)(1 + d) * KK];

  float beta  = (lane == START_TAG) ? 1.0f : 0.0f;
  int   esum  = 0;                      // sum of pow2 exponents (exact)
  float f_cur = __expf(upf[0]);         // exp(u_1)

  for (int g = 0; g < 73; ++g) {
    #pragma unroll
    for (int d = 0; d < 7; ++d) {
      const int t = 1 + g * 7 + d;

      // z_i = sum_j E[i][j]*beta[j]; beta[j] via readlane->SGPR broadcast.
      // 8 independent accumulator chains; all readlanes independent.
      float a0 = 0.f, a1 = 0.f, a2 = 0.f, a3 = 0.f;
      float a4 = 0.f, a5 = 0.f, a6 = 0.f, a7 = 0.f;
      #pragma unroll
      for (int j = 0; j < KK; j += 8) {
        a0 = fmaf(e[j + 0], RLF(beta, j + 0), a0);
        a1 = fmaf(e[j + 1], RLF(beta, j + 1), a1);
        a2 = fmaf(e[j + 2], RLF(beta, j + 2), a2);
        a3 = fmaf(e[j + 3], RLF(beta, j + 3), a3);
        a4 = fmaf(e[j + 4], RLF(beta, j + 4), a4);
        a5 = fmaf(e[j + 5], RLF(beta, j + 5), a5);
        a6 = fmaf(e[j + 6], RLF(beta, j + 6), a6);
        a7 = fmaf(e[j + 7], RLF(beta, j + 7), a7);
      }
      float z = ((a0 + a1) + (a2 + a3)) + ((a4 + a5) + (a6 + a7));

      // refill slot d with u_{t+7} (clamped; slot consumed at step t-1)
      int tn = t + 7; if (tn > TT - 1) tn = TT - 1;
      upf[d] = fb[(size_t)tn * KK];

      // ---- fresh pow2 normalization; exponent bookkeeping on SALU ----
      unsigned zb = (unsigned)__builtin_amdgcn_readlane((int)__float_as_uint(z), 0);
      float s = __uint_as_float(0x7F000000u - (zb & 0x7F800000u)); // 2^-(e-127)
      esum += (int)((zb >> 23) & 0xFFu) - 127;
      beta = (z * f_cur) * s;           // z*f issues while s resolves

      // next step's feat factor (off critical path; feats don't feed back)
      f_cur = __expf((d < 6) ? upf[d + 1] : upf[0]);
    }
  }

  // forward score = log(sum_j beta) + esum*ln2
  float bs = beta;
  #pragma unroll
  for (int off = 32; off; off >>= 1) bs += __shfl_xor(bs, off);
  float fwd = __logf(bs) + (float)esum * 0.6931471805599453f;

  // ---- gold path score ----
  const int* tg = tags + b * TT;
  float gs = 0.0f;
  for (int tt = 1 + lane; tt < TT; tt += 64) {
    int tc = tg[tt];
    int tp = tg[tt - 1];
    gs += trans[tc * KK + tp]
        + feats[(size_t)b * TT * KK + (size_t)tt * KK + tc];
  }
  #pragma unroll
  for (int off = 32; off; off >>= 1) gs += __shfl_xor(gs, off);

  if (lane == 0) diff[b] = fwd - gs;
}

__global__ __launch_bounds__(1024) void reduce_mean_kernel(
    const float* __restrict__ diff, float* __restrict__ out)
{
  __shared__ float part[16];
  const int tid = threadIdx.x;
  float v = diff[tid];
  #pragma unroll
  for (int off = 32; off; off >>= 1) v += __shfl_xor(v, off);
  if ((tid & 63) == 0) part[tid >> 6] = v;
  __syncthreads();
  if (tid < 16) {
    float s = part[tid];
    #pragma unroll
    for (int off = 8; off; off >>= 1) s += __shfl_xor(s, off);
    if (tid == 0) out[0] = s * (1.0f / 1024.0f);
  }
}

extern "C" void kernel_launch(void* const* d_in, const int* in_sizes, int n_in,
                              void* d_out, int out_size, void* d_ws, size_t ws_size,
                              hipStream_t stream) {
  const float* feats = (const float*)d_in[0];
  const int*   tags  = (const int*)d_in[1];
  const float* trans = (const float*)d_in[2];
  float* out  = (float*)d_out;
  float* diff = (float*)d_ws;   // 1024 floats of scratch

  crf_forward_kernel<<<dim3(BB), dim3(64), 0, stream>>>(feats, tags, trans, diff);
  reduce_mean_kernel<<<dim3(1), dim3(1024), 0, stream>>>(diff, out);
}